// Round 1
// 563.870 us; speedup vs baseline: 1.3711x; 1.3711x over previous
//
#include <hip/hip_runtime.h>

#define B_ 16
#define C_ 512
#define K_ 128
#define N_ 4096   // H*W = 64*64
#define NKEEP 51  // int(0.1 * 512)
#define NSPLIT 8  // n-reduction split for qk (8 image rows per block)

// ---------------------------------------------------------------------------
// K1: depthwise 3x3 conv (SAME, stride 1) for k and v from x_kv.
// One thread per output pixel; computes both k and v from the same 3x3 reads.
__global__ void conv_kv_kernel(const float* __restrict__ xkv,
                               const float* __restrict__ wk, const float* __restrict__ bk,
                               const float* __restrict__ wv, const float* __restrict__ bv,
                               float* __restrict__ kb, float* __restrict__ vb) {
    int idx = blockIdx.x * 256 + threadIdx.x;   // over B*K*H*W = 8388608
    int x = idx & 63;
    int y = (idx >> 6) & 63;
    int k = (idx >> 12) & 127;
    int b = idx >> 19;
    const float* wkp = wk + k * 9;
    const float* wvp = wv + k * 9;
    const float* xp  = xkv + (size_t)(b * K_ + k) * N_;
    float ak = bk[k], av = bv[k];
#pragma unroll
    for (int dy = 0; dy < 3; ++dy) {
        int yy = y + dy - 1;
        if (yy < 0 || yy > 63) continue;
#pragma unroll
        for (int dx = 0; dx < 3; ++dx) {
            int xx = x + dx - 1;
            if (xx < 0 || xx > 63) continue;
            float xv = xp[yy * 64 + xx];
            ak += xv * wkp[dy * 3 + dx];
            av += xv * wvp[dy * 3 + dx];
        }
    }
    kb[idx] = ak;
    vb[idx] = av;
}

// ---------------------------------------------------------------------------
// K2: partial logits. Block = (b, 64-channel tile, 8-image-row n-chunk).
// part[ns][b][c][k] = sum over the chunk's 512 n of q[b,c,n]*k[b,k,n]
// q is computed on the fly (depthwise conv on x_q) during staging.
// Inner: 4c x 8k register tile per thread, [n][c]/[n][k] LDS layouts so
// compute reads broadcast across lanes (LDS pipe stays off the critical path).
__global__ __launch_bounds__(256) void qk2_kernel(const float* __restrict__ xq,
                                                  const float* __restrict__ wq,
                                                  const float* __restrict__ bq,
                                                  const float* __restrict__ kb,
                                                  float* __restrict__ part) {
    __shared__ float qs[64][64];    // [n within row][c]   16 KiB
    __shared__ float ks[64][128];   // [n within row][k]   32 KiB
    int blk = blockIdx.x;
    int ct  = blk & 7;              // 8 c-tiles of 64 (consecutive blocks share kb chunk)
    int ns  = (blk >> 3) & 7;       // 8 n-chunks
    int b   = blk >> 6;
    int c0  = ct * 64;
    int r0  = ns * 8;
    int tid = threadIdx.x;

    // conv staging role: channel c_l, 16-pixel x-segment
    int c_l = tid >> 2;             // 0..63
    int xs  = (tid & 3) << 4;       // 0,16,32,48
    // k staging role: k-row, 32-pixel half
    int k_l = tid >> 1;             // 0..127
    int nh  = (tid & 1) << 5;       // 0,32
    // compute role: 16 c-groups x 16 k-groups
    int cg4 = (tid & 15) * 4;       // c offset within tile
    int kg8 = (tid >> 4) * 8;       // k offset

    // preload conv weights for channel c0+c_l
    const float* wp = wq + (size_t)(c0 + c_l) * 9;
    float w00=wp[0],w01=wp[1],w02=wp[2],w10=wp[3],w11=wp[4],w12=wp[5],w20=wp[6],w21=wp[7],w22=wp[8];
    float bias = bq[c0 + c_l];
    const float* xqp = xq + ((size_t)(b * C_) + c0 + c_l) * N_;
    const float* kbp = kb + ((size_t)(b * K_) + k_l) * N_;

    float acc[4][8];
#pragma unroll
    for (int i = 0; i < 4; ++i)
#pragma unroll
        for (int j = 0; j < 8; ++j) acc[i][j] = 0.f;

    for (int rr = 0; rr < 8; ++rr) {
        int r = r0 + rr;
        __syncthreads();
        // ---- stage ks[n][k]: row r of k-plane k_l (2-way write, free) ----
        {
            const float4* src = (const float4*)(kbp + r * 64 + nh);
#pragma unroll
            for (int m = 0; m < 8; ++m) {
                float4 v = src[m];
                int nn = nh + m * 4;
                ks[nn][k_l] = v.x; ks[nn + 1][k_l] = v.y;
                ks[nn + 2][k_l] = v.z; ks[nn + 3][k_l] = v.w;
            }
        }
        // ---- stage qs[n][c]: conv on the fly, 16 pixels of row r, ch c_l ----
        {
            float a16[16];
#pragma unroll
            for (int i = 0; i < 16; ++i) a16[i] = bias;
#pragma unroll
            for (int dy = 0; dy < 3; ++dy) {
                int yy = r + dy - 1;
                if (yy < 0 || yy > 63) continue;
                const float* row = xqp + yy * 64;
                float wa = (dy == 0) ? w00 : (dy == 1) ? w10 : w20;
                float wb = (dy == 0) ? w01 : (dy == 1) ? w11 : w21;
                float wc = (dy == 0) ? w02 : (dy == 1) ? w12 : w22;
                float p = (xs == 0) ? 0.f : row[xs - 1];
                float c = row[xs];
#pragma unroll
                for (int i = 0; i < 16; ++i) {
                    int x = xs + i;
                    float n = (x == 63) ? 0.f : row[x + 1];
                    a16[i] += p * wa + c * wb + n * wc;
                    p = c; c = n;
                }
            }
#pragma unroll
            for (int i = 0; i < 16; ++i) qs[xs + i][c_l] = a16[i];
        }
        __syncthreads();
        // ---- accumulate 4c x 8k outer products over this row ----
#pragma unroll 4
        for (int nn = 0; nn < 64; ++nn) {
            float4 q4  = *(const float4*)&qs[nn][cg4];
            float4 k4a = *(const float4*)&ks[nn][kg8];
            float4 k4b = *(const float4*)&ks[nn][kg8 + 4];
            float qa[4] = {q4.x, q4.y, q4.z, q4.w};
            float kk[8] = {k4a.x, k4a.y, k4a.z, k4a.w, k4b.x, k4b.y, k4b.z, k4b.w};
#pragma unroll
            for (int i = 0; i < 4; ++i)
#pragma unroll
                for (int j = 0; j < 8; ++j) acc[i][j] += qa[i] * kk[j];
        }
    }
    // write partials: part[ns][b][c][k]
    float* dst = part + (((size_t)ns * B_ + b) * C_ + c0 + cg4) * K_ + kg8;
#pragma unroll
    for (int i = 0; i < 4; ++i) {
        *(float4*)(dst + (size_t)i * K_)     = make_float4(acc[i][0], acc[i][1], acc[i][2], acc[i][3]);
        *(float4*)(dst + (size_t)i * K_ + 4) = make_float4(acc[i][4], acc[i][5], acc[i][6], acc[i][7]);
    }
}

// ---------------------------------------------------------------------------
// K3: reduce NSPLIT partials, scale by 1/sqrt(128), softmax over k (128)
// per (b,c) row. One wave per row.
__global__ void softmax_kernel(const float* __restrict__ part, float* __restrict__ aw) {
    int tid  = threadIdx.x;
    int wave = tid >> 6;
    int lane = tid & 63;
    int row  = blockIdx.x * 4 + wave;   // over B*C = 8192
    float v0 = 0.f, v1 = 0.f;
#pragma unroll
    for (int ns = 0; ns < NSPLIT; ++ns) {
        const float* p = part + ((size_t)ns * B_ * C_ + row) * K_;
        v0 += p[lane];
        v1 += p[lane + 64];
    }
    const float scale = 0.08838834764831845f; // 1/sqrt(128)
    v0 *= scale; v1 *= scale;
    float m = fmaxf(v0, v1);
#pragma unroll
    for (int s = 32; s >= 1; s >>= 1) m = fmaxf(m, __shfl_xor(m, s, 64));
    float e0 = __expf(v0 - m), e1 = __expf(v1 - m);
    float s = e0 + e1;
#pragma unroll
    for (int t = 32; t >= 1; t >>= 1) s += __shfl_xor(s, t, 64);
    float inv = 1.0f / s;
    float* q = aw + (size_t)row * K_;
    q[lane] = e0 * inv;
    q[lane + 64] = e1 * inv;
}

// ---------------------------------------------------------------------------
// K4: per (b,k) column over c (512): find 51st-largest exactly via binary
// search on float bit pattern (positive floats order as uints), zero the rest.
__global__ void topk_mask_kernel(float* __restrict__ aw) {
    int tid  = threadIdx.x;
    int wave = tid >> 6, lane = tid & 63;
    int col  = blockIdx.x * 4 + wave;   // over B*K = 2048
    int b = col >> 7, k = col & 127;
    float* base = aw + (size_t)(b * C_) * K_ + k;
    unsigned u[8];
#pragma unroll
    for (int j = 0; j < 8; ++j)
        u[j] = __float_as_uint(base[(size_t)(j * 64 + lane) * K_]);
    unsigned T = 0;
#pragma unroll
    for (int bit = 31; bit >= 0; --bit) {
        unsigned cand = T | (1u << bit);
        int cnt = 0;
#pragma unroll
        for (int j = 0; j < 8; ++j) cnt += (u[j] >= cand) ? 1 : 0;
#pragma unroll
        for (int s = 32; s >= 1; s >>= 1) cnt += __shfl_xor(cnt, s, 64);
        if (cnt >= NKEEP) T = cand;
    }
#pragma unroll
    for (int j = 0; j < 8; ++j)
        if (u[j] < T) base[(size_t)(j * 64 + lane) * K_] = 0.0f;
}

// ---------------------------------------------------------------------------
// K5: attn_out = aw_masked @ v ; out0 = x_q + attn_out.
// Block tile: 32 c x 256 n, inner k chunked by 16.
__global__ __launch_bounds__(256) void av_kernel(const float* __restrict__ aw,
                                                 const float* __restrict__ vb,
                                                 const float* __restrict__ xq,
                                                 float* __restrict__ out) {
    __shared__ float vs[16][260];   // [k][n], pad 256->260
    __shared__ float aws[16][36];   // [k][c], pad 32->36
    int blk  = blockIdx.x;
    int b    = blk >> 8;
    int rest = blk & 255;
    int c0 = (rest >> 4) * 32;
    int n0 = (rest & 15) * 256;
    int tid = threadIdx.x;
    int cg = tid >> 5;              // 0..7, cbase = cg*4
    int ng = tid & 31;              // nbase = ng*8
    int k_l = tid >> 4;             // 0..15 (vs staging row)
    int nn0 = (tid & 15) * 16;

    float acc[4][8];
#pragma unroll
    for (int i = 0; i < 4; ++i)
#pragma unroll
        for (int j = 0; j < 8; ++j) acc[i][j] = 0.f;

    for (int kc = 0; kc < K_; kc += 16) {
        __syncthreads();
        // stage vs[k][n]: natural layout, float4
        {
            const float4* src = (const float4*)(vb + (size_t)(b * K_ + kc + k_l) * N_ + n0 + nn0);
            float4* dst = (float4*)&vs[k_l][nn0];
#pragma unroll
            for (int m = 0; m < 4; ++m) dst[m] = src[m];
        }
        // stage aws transposed: [k][c]
        {
            int i0 = tid * 2;
#pragma unroll
            for (int t2 = 0; t2 < 2; ++t2) {
                int i = i0 + t2;
                int cc = i >> 4;    // 0..31
                int kk = i & 15;
                aws[kk][cc] = aw[(size_t)(b * C_ + c0 + cc) * K_ + kc + kk];
            }
        }
        __syncthreads();
#pragma unroll
        for (int kk = 0; kk < 16; ++kk) {
            float4 a4  = *(const float4*)&aws[kk][cg * 4];
            float4 v4a = *(const float4*)&vs[kk][ng * 8];
            float4 v4b = *(const float4*)&vs[kk][ng * 8 + 4];
            float aa[4] = {a4.x, a4.y, a4.z, a4.w};
            float av[8] = {v4a.x, v4a.y, v4a.z, v4a.w, v4b.x, v4b.y, v4b.z, v4b.w};
#pragma unroll
            for (int i = 0; i < 4; ++i)
#pragma unroll
                for (int j = 0; j < 8; ++j) acc[i][j] += aa[i] * av[j];
        }
    }
    // epilogue: out = x_q + acc, vectorized
#pragma unroll
    for (int i = 0; i < 4; ++i) {
        int c = c0 + cg * 4 + i;
        size_t base = (size_t)(b * C_ + c) * N_ + n0 + ng * 8;
        const float4* xp4 = (const float4*)(xq + base);
        float4* op4 = (float4*)(out + base);
        float4 x0 = xp4[0], x1 = xp4[1];
        float4 o0, o1;
        o0.x = x0.x + acc[i][0]; o0.y = x0.y + acc[i][1];
        o0.z = x0.z + acc[i][2]; o0.w = x0.w + acc[i][3];
        o1.x = x1.x + acc[i][4]; o1.y = x1.y + acc[i][5];
        o1.z = x1.z + acc[i][6]; o1.w = x1.w + acc[i][7];
        op4[0] = o0; op4[1] = o1;
    }
}

// ---------------------------------------------------------------------------
extern "C" void kernel_launch(void* const* d_in, const int* in_sizes, int n_in,
                              void* d_out, int out_size, void* d_ws, size_t ws_size,
                              hipStream_t stream) {
    const float* xq  = (const float*)d_in[0];
    const float* xkv = (const float*)d_in[1];
    const float* wq  = (const float*)d_in[2];
    const float* bq  = (const float*)d_in[3];
    const float* wk  = (const float*)d_in[4];
    const float* bk  = (const float*)d_in[5];
    const float* wv  = (const float*)d_in[6];
    const float* bv  = (const float*)d_in[7];

    float* out0 = (float*)d_out;                       // [16,512,64,64]
    float* aw   = out0 + (size_t)B_ * C_ * N_;         // [16,512,128]

    float* kb = (float*)d_ws;                          // [16,128,4096]
    float* vb = kb + (size_t)B_ * K_ * N_;             // [16,128,4096]
    // qk partials scratch: reuse out0's memory (33.5 MB of its 134 MB);
    // K5 fully overwrites out0 afterwards and never reads it.
    float* part = out0;                                // [NSPLIT][16][512][128]

    // 1. depthwise conv for k, v
    conv_kv_kernel<<<(B_ * K_ * N_) / 256, 256, 0, stream>>>(xkv, wk, bk, wv, bv, kb, vb);
    // 2. partial logits, q conv fused; 16b x 8 n-chunks x 8 c-tiles
    qk2_kernel<<<B_ * 64, 256, 0, stream>>>(xq, wq, bq, kb, part);
    // 3. reduce partials + scale + softmax over k
    softmax_kernel<<<(B_ * C_) / 4, 256, 0, stream>>>(part, aw);
    // 4. top-51 along c per (b,k), mask in place
    topk_mask_kernel<<<(B_ * K_) / 4, 256, 0, stream>>>(aw);
    // 5. attn_out = aw @ v + x_q
    av_kernel<<<B_ * 256, 256, 0, stream>>>(aw, vb, xq, out0);
}